// Round 1
// baseline (253.868 us; speedup 1.0000x reference)
//
#include <hip/hip_runtime.h>
#include <hip/hip_bf16.h>

// NTM cell on MI355X. Sizes (compile-time constants):
// B=2048, IN=64, CTRL=512, M=1024, V=64, OUT=64
// All GEMMs are NT (A: MxK row-major, B: NxK row-major) -> bf16 MFMA 16x16x32.

typedef unsigned short u16;
typedef __attribute__((ext_vector_type(8))) short bf16x8;
typedef __attribute__((ext_vector_type(4))) float f32x4;

#define MFMA_BF16(a, b, c) __builtin_amdgcn_mfma_f32_16x16x32_bf16((a), (b), (c), 0, 0, 0)

__device__ __forceinline__ u16 f2bf(float f) {
    union { float f; unsigned int u; } a; a.f = f;
    unsigned int r = (a.u + 0x7FFFu + ((a.u >> 16) & 1u)) >> 16;
    return (u16)r;
}

__device__ __forceinline__ void pack_store4(float a0, float a1, float a2, float a3, u16* d) {
    __hip_bfloat162 lo = __float22bfloat162_rn(make_float2(a0, a1));
    __hip_bfloat162 hi = __float22bfloat162_rn(make_float2(a2, a3));
    union { __hip_bfloat162 h[2]; uint2 u; } cv;
    cv.h[0] = lo; cv.h[1] = hi;
    *(uint2*)d = cv.u;
}

__device__ __forceinline__ void cvt4(const float* __restrict__ s, u16* __restrict__ d) {
    float4 v = *(const float4*)s;
    pack_store4(v.x, v.y, v.z, v.w, d);
}

__device__ __forceinline__ float sigf(float x) { return 1.f / (1.f + __expf(-x)); }
__device__ __forceinline__ float fast_tanh(float x) { return 1.f - 2.f / (__expf(2.f * x) + 1.f); }

// ---------------------------------------------------------------------------
// Convert all fp32 operands to bf16 in workspace (+ transpose memory).
// Jobs indexed in float4 units; grid sized exactly to the total.
// ---------------------------------------------------------------------------
__global__ __launch_bounds__(256) void k_convert(
    const float* __restrict__ x, const float* __restrict__ h_prev, const float* __restrict__ rwp,
    const float* __restrict__ memory, const float* __restrict__ W_ih, const float* __restrict__ W_hh,
    const float* __restrict__ W_read, const float* __restrict__ W_write, const float* __restrict__ W_erase,
    const float* __restrict__ W_add, const float* __restrict__ W_out,
    u16* inp_h, u16* wcat, u16* rwp_bf, u16* memt, u16* Wr, u16* Ww, u16* Wea, u16* Wo)
{
    int t = blockIdx.x * 256 + threadIdx.x;
    if (t < 32768) { int r = t >> 4, c = (t & 15) * 4; cvt4(x + r * 64 + c, inp_h + r * 640 + c); return; }
    t -= 32768;
    if (t < 262144) { int r = t >> 7, c = (t & 127) * 4; cvt4(h_prev + r * 512 + c, inp_h + r * 640 + 128 + c); return; }
    t -= 262144;
    if (t < 65536) { int r = t >> 5, c = (t & 31) * 4; cvt4(W_ih + r * 128 + c, wcat + r * 640 + c); return; }
    t -= 65536;
    if (t < 262144) { int r = t >> 7, c = (t & 127) * 4; cvt4(W_hh + r * 512 + c, wcat + r * 640 + 128 + c); return; }
    t -= 262144;
    if (t < 524288) { int r = t >> 8, c = (t & 255) * 4; cvt4(rwp + r * 1024 + c, rwp_bf + r * 1024 + c); return; }
    t -= 524288;
    if (t < 131072) { int r = t >> 7, c = (t & 127) * 4; cvt4(W_read + r * 512 + c, Wr + r * 512 + c); return; }
    t -= 131072;
    if (t < 131072) { int r = t >> 7, c = (t & 127) * 4; cvt4(W_write + r * 512 + c, Ww + r * 512 + c); return; }
    t -= 131072;
    if (t < 8192) { int r = t >> 7, c = (t & 127) * 4; cvt4(W_erase + r * 512 + c, Wea + r * 512 + c); return; }
    t -= 8192;
    if (t < 8192) { int r = t >> 7, c = (t & 127) * 4; cvt4(W_add + r * 512 + c, Wea + (64 + r) * 512 + c); return; }
    t -= 8192;
    if (t < 9216) { int r = t / 144, c = (t % 144) * 4; cvt4(W_out + r * 576 + c, Wo + r * 576 + c); return; }
    t -= 9216;
    if (t < 16384) {
        int v = t >> 8, m = (t & 255) * 4;
        float a0 = memory[(m + 0) * 64 + v];
        float a1 = memory[(m + 1) * 64 + v];
        float a2 = memory[(m + 2) * 64 + v];
        float a3 = memory[(m + 3) * 64 + v];
        pack_store4(a0, a1, a2, a3, memt + v * 1024 + m);
    }
}

// ---------------------------------------------------------------------------
// Generic NT GEMM core. Block = 256 threads (4 waves), tile BM=128 x BN=64,
// BK=64. Wave w computes rows [32w,32w+32) x all 64 cols: 2x4 MFMA tiles.
// LDS rows padded to 72 elements (144B): frag reads are 2-way bank aliased
// (free per m136); staging writes conflict-free.
// ---------------------------------------------------------------------------
template <int KTILES, typename EPI>
__device__ __forceinline__ void gemm_nt_core(
    const u16* __restrict__ A, int lda,
    const u16* __restrict__ B, int ldb,
    int m0, int n0, EPI epi)
{
    __shared__ u16 As[128 * 72];
    __shared__ u16 Bs[64 * 72];
    const int tid = threadIdx.x;
    const int w = tid >> 6, lane = tid & 63;
    const int lrow = lane & 15, lq = lane >> 4;

    f32x4 acc[2][4] = {};

    for (int kt = 0; kt < KTILES; ++kt) {
        const u16* Ak = A + m0 * lda + kt * 64;
        const u16* Bk = B + n0 * ldb + kt * 64;
#pragma unroll
        for (int i = 0; i < 4; ++i) {
            int idx = i * 256 + tid;
            int r = idx >> 3, c = (idx & 7) * 8;
            uint4 v = *(const uint4*)(Ak + r * lda + c);
            *(uint4*)(&As[r * 72 + c]) = v;
        }
#pragma unroll
        for (int i = 0; i < 2; ++i) {
            int idx = i * 256 + tid;
            int r = idx >> 3, c = (idx & 7) * 8;
            uint4 v = *(const uint4*)(Bk + r * ldb + c);
            *(uint4*)(&Bs[r * 72 + c]) = v;
        }
        __syncthreads();
#pragma unroll
        for (int kk = 0; kk < 64; kk += 32) {
            bf16x8 a0 = *(const bf16x8*)(&As[(32 * w + lrow) * 72 + kk + 8 * lq]);
            bf16x8 a1 = *(const bf16x8*)(&As[(32 * w + 16 + lrow) * 72 + kk + 8 * lq]);
            bf16x8 b0 = *(const bf16x8*)(&Bs[(lrow) * 72 + kk + 8 * lq]);
            bf16x8 b1 = *(const bf16x8*)(&Bs[(16 + lrow) * 72 + kk + 8 * lq]);
            bf16x8 b2 = *(const bf16x8*)(&Bs[(32 + lrow) * 72 + kk + 8 * lq]);
            bf16x8 b3 = *(const bf16x8*)(&Bs[(48 + lrow) * 72 + kk + 8 * lq]);
            acc[0][0] = MFMA_BF16(a0, b0, acc[0][0]);
            acc[0][1] = MFMA_BF16(a0, b1, acc[0][1]);
            acc[0][2] = MFMA_BF16(a0, b2, acc[0][2]);
            acc[0][3] = MFMA_BF16(a0, b3, acc[0][3]);
            acc[1][0] = MFMA_BF16(a1, b0, acc[1][0]);
            acc[1][1] = MFMA_BF16(a1, b1, acc[1][1]);
            acc[1][2] = MFMA_BF16(a1, b2, acc[1][2]);
            acc[1][3] = MFMA_BF16(a1, b3, acc[1][3]);
        }
        __syncthreads();
    }
#pragma unroll
    for (int mi = 0; mi < 2; ++mi)
#pragma unroll
        for (int nj = 0; nj < 4; ++nj)
#pragma unroll
            for (int r = 0; r < 4; ++r) {
                int grow = m0 + 32 * w + 16 * mi + 4 * lq + r;
                int gcol = n0 + 16 * nj + lrow;
                epi(grow, gcol, acc[mi][nj][r]);
            }
}

// read_prev = read_weights_prev @ memory  -> bf16 into inp_h cols 64..127
__global__ __launch_bounds__(256) void k_gemm_readprev(const u16* __restrict__ rwp_bf,
                                                       const u16* __restrict__ memt,
                                                       u16* __restrict__ inp_h)
{
    gemm_nt_core<16>(rwp_bf, 1024, memt, 1024, blockIdx.x * 128, 0,
        [&](int r, int c, float v) { inp_h[r * 640 + 64 + c] = f2bf(v); });
}

// gates = [x|read_prev|h_prev] @ [W_ih|W_hh]^T + b_ih + b_hh  (fp32, ld 2048)
__global__ __launch_bounds__(256) void k_gates(const u16* __restrict__ inp_h, const u16* __restrict__ wcat,
                                               const float* __restrict__ b_ih, const float* __restrict__ b_hh,
                                               float* __restrict__ gates)
{
    gemm_nt_core<10>(inp_h, 640, wcat, 640, blockIdx.x * 128, blockIdx.y * 64,
        [&](int r, int c, float v) { gates[r * 2048 + c] = v + b_ih[c] + b_hh[c]; });
}

// LSTM elementwise: h -> hrn_bf cols 0..511
__global__ __launch_bounds__(256) void k_lstm(const float* __restrict__ gates,
                                              const float* __restrict__ c_prev,
                                              u16* __restrict__ hrn)
{
    int t = blockIdx.x * 256 + threadIdx.x;   // 2048*512 threads
    int b = t >> 9, j = t & 511;
    const float* g = gates + b * 2048;
    float ig = sigf(g[j]);
    float fg = sigf(g[512 + j]);
    float gg = fast_tanh(g[1024 + j]);
    float og = sigf(g[1536 + j]);
    float c = fg * c_prev[t] + ig * gg;
    float h = og * fast_tanh(c);
    hrn[b * 576 + j] = f2bf(h);
}

// pre_read / pre_write = h @ W_{read,write}^T + bias (fp32, ld 1024)
__global__ __launch_bounds__(256) void k_rdwr(const u16* __restrict__ hrn,
                                              const u16* __restrict__ Wr, const u16* __restrict__ Ww,
                                              const float* __restrict__ br, const float* __restrict__ bw,
                                              float* __restrict__ pr, float* __restrict__ pw)
{
    const u16* Bm = blockIdx.z ? Ww : Wr;
    const float* bias = blockIdx.z ? bw : br;
    float* out = blockIdx.z ? pw : pr;
    gemm_nt_core<8>(hrn, 576, Bm, 512, blockIdx.x * 128, blockIdx.y * 64,
        [&](int r, int c, float v) { out[r * 1024 + c] = v + bias[c]; });
}

// erase = sigmoid(h @ W_erase^T + b), add = tanh(h @ W_add^T + b)
__global__ __launch_bounds__(256) void k_ea(const u16* __restrict__ hrn, const u16* __restrict__ Wea,
                                            const float* __restrict__ b_er, const float* __restrict__ b_ad,
                                            float* __restrict__ erase, float* __restrict__ add)
{
    gemm_nt_core<8>(hrn, 576, Wea, 512, blockIdx.x * 128, blockIdx.y * 64,
        [&](int r, int c, float v) {
            if (c < 64) erase[r * 64 + c] = sigf(v + b_er[c]);
            else        add[r * 64 + (c - 64)] = fast_tanh(v + b_ad[c - 64]);
        });
}

__device__ __forceinline__ float wave_max(float v) {
#pragma unroll
    for (int o = 32; o > 0; o >>= 1) v = fmaxf(v, __shfl_xor(v, o, 64));
    return v;
}
__device__ __forceinline__ float wave_sum(float v) {
#pragma unroll
    for (int o = 32; o > 0; o >>= 1) v += __shfl_xor(v, o, 64);
    return v;
}

// dual softmax over M=1024; emits rw_bf, rw2_bf = rw*ww (bf16), s[b] = sum(rw*ww)
__global__ __launch_bounds__(256) void k_softmax(const float* __restrict__ pr, const float* __restrict__ pw,
                                                 u16* __restrict__ rw_bf, u16* __restrict__ rw2_bf,
                                                 float* __restrict__ s)
{
    int b = blockIdx.x, tid = threadIdx.x, w = tid >> 6, lane = tid & 63;
    const float* prb = pr + b * 1024;
    const float* pwb = pw + b * 1024;
    float vr[4], vw[4];
#pragma unroll
    for (int i = 0; i < 4; ++i) { vr[i] = prb[tid + 256 * i]; vw[i] = pwb[tid + 256 * i]; }
    float mr = fmaxf(fmaxf(vr[0], vr[1]), fmaxf(vr[2], vr[3]));
    float mw = fmaxf(fmaxf(vw[0], vw[1]), fmaxf(vw[2], vw[3]));
    mr = wave_max(mr); mw = wave_max(mw);
    __shared__ float red[4][4];
    if (lane == 0) { red[0][w] = mr; red[1][w] = mw; }
    __syncthreads();
    mr = fmaxf(fmaxf(red[0][0], red[0][1]), fmaxf(red[0][2], red[0][3]));
    mw = fmaxf(fmaxf(red[1][0], red[1][1]), fmaxf(red[1][2], red[1][3]));
    float er[4], ew[4], sr = 0.f, sw = 0.f;
#pragma unroll
    for (int i = 0; i < 4; ++i) {
        er[i] = __expf(vr[i] - mr); sr += er[i];
        ew[i] = __expf(vw[i] - mw); sw += ew[i];
    }
    sr = wave_sum(sr); sw = wave_sum(sw);
    __syncthreads();
    if (lane == 0) { red[2][w] = sr; red[3][w] = sw; }
    __syncthreads();
    sr = red[2][0] + red[2][1] + red[2][2] + red[2][3];
    sw = red[3][0] + red[3][1] + red[3][2] + red[3][3];
    float isr = 1.f / sr, isw = 1.f / sw, ss = 0.f;
#pragma unroll
    for (int i = 0; i < 4; ++i) {
        float a = er[i] * isr, cc = ew[i] * isw, r2 = a * cc;
        ss += r2;
        rw_bf[b * 1024 + tid + 256 * i] = f2bf(a);
        rw2_bf[b * 1024 + tid + 256 * i] = f2bf(r2);
    }
    ss = wave_sum(ss);
    __syncthreads();
    if (lane == 0) red[0][w] = ss;
    __syncthreads();
    if (tid == 0) s[b] = red[0][0] + red[0][1] + red[0][2] + red[0][3];
}

// read_new = rw@mem - erase * (rw*ww)@mem + add * s  -> bf16 into hrn cols 512..575
__global__ __launch_bounds__(256) void k_readnew(const u16* __restrict__ rw, const u16* __restrict__ rw2,
                                                 const u16* __restrict__ memt,
                                                 const float* __restrict__ erase, const float* __restrict__ add,
                                                 const float* __restrict__ s, u16* __restrict__ hrn)
{
    __shared__ u16 As1[128 * 72];
    __shared__ u16 As2[128 * 72];
    __shared__ u16 Bs[64 * 72];
    const int tid = threadIdx.x;
    const int w = tid >> 6, lane = tid & 63;
    const int lrow = lane & 15, lq = lane >> 4;
    const int m0 = blockIdx.x * 128;

    f32x4 acc1[2][4] = {}, acc2[2][4] = {};

    for (int kt = 0; kt < 16; ++kt) {
        const u16* A1k = rw + m0 * 1024 + kt * 64;
        const u16* A2k = rw2 + m0 * 1024 + kt * 64;
        const u16* Bk = memt + kt * 64;
#pragma unroll
        for (int i = 0; i < 4; ++i) {
            int idx = i * 256 + tid;
            int r = idx >> 3, c = (idx & 7) * 8;
            *(uint4*)(&As1[r * 72 + c]) = *(const uint4*)(A1k + r * 1024 + c);
            *(uint4*)(&As2[r * 72 + c]) = *(const uint4*)(A2k + r * 1024 + c);
        }
#pragma unroll
        for (int i = 0; i < 2; ++i) {
            int idx = i * 256 + tid;
            int r = idx >> 3, c = (idx & 7) * 8;
            *(uint4*)(&Bs[r * 72 + c]) = *(const uint4*)(Bk + r * 1024 + c);
        }
        __syncthreads();
#pragma unroll
        for (int kk = 0; kk < 64; kk += 32) {
            bf16x8 a0 = *(const bf16x8*)(&As1[(32 * w + lrow) * 72 + kk + 8 * lq]);
            bf16x8 a1 = *(const bf16x8*)(&As1[(32 * w + 16 + lrow) * 72 + kk + 8 * lq]);
            bf16x8 c0 = *(const bf16x8*)(&As2[(32 * w + lrow) * 72 + kk + 8 * lq]);
            bf16x8 c1 = *(const bf16x8*)(&As2[(32 * w + 16 + lrow) * 72 + kk + 8 * lq]);
            bf16x8 b0 = *(const bf16x8*)(&Bs[(lrow) * 72 + kk + 8 * lq]);
            bf16x8 b1 = *(const bf16x8*)(&Bs[(16 + lrow) * 72 + kk + 8 * lq]);
            bf16x8 b2 = *(const bf16x8*)(&Bs[(32 + lrow) * 72 + kk + 8 * lq]);
            bf16x8 b3 = *(const bf16x8*)(&Bs[(48 + lrow) * 72 + kk + 8 * lq]);
            acc1[0][0] = MFMA_BF16(a0, b0, acc1[0][0]);
            acc1[0][1] = MFMA_BF16(a0, b1, acc1[0][1]);
            acc1[0][2] = MFMA_BF16(a0, b2, acc1[0][2]);
            acc1[0][3] = MFMA_BF16(a0, b3, acc1[0][3]);
            acc1[1][0] = MFMA_BF16(a1, b0, acc1[1][0]);
            acc1[1][1] = MFMA_BF16(a1, b1, acc1[1][1]);
            acc1[1][2] = MFMA_BF16(a1, b2, acc1[1][2]);
            acc1[1][3] = MFMA_BF16(a1, b3, acc1[1][3]);
            acc2[0][0] = MFMA_BF16(c0, b0, acc2[0][0]);
            acc2[0][1] = MFMA_BF16(c0, b1, acc2[0][1]);
            acc2[0][2] = MFMA_BF16(c0, b2, acc2[0][2]);
            acc2[0][3] = MFMA_BF16(c0, b3, acc2[0][3]);
            acc2[1][0] = MFMA_BF16(c1, b0, acc2[1][0]);
            acc2[1][1] = MFMA_BF16(c1, b1, acc2[1][1]);
            acc2[1][2] = MFMA_BF16(c1, b2, acc2[1][2]);
            acc2[1][3] = MFMA_BF16(c1, b3, acc2[1][3]);
        }
        __syncthreads();
    }
#pragma unroll
    for (int mi = 0; mi < 2; ++mi)
#pragma unroll
        for (int nj = 0; nj < 4; ++nj)
#pragma unroll
            for (int r = 0; r < 4; ++r) {
                int grow = m0 + 32 * w + 16 * mi + 4 * lq + r;
                int gcol = 16 * nj + lrow;
                float rn = acc1[mi][nj][r] - erase[grow * 64 + gcol] * acc2[mi][nj][r]
                         + add[grow * 64 + gcol] * s[grow];
                hrn[grow * 576 + 512 + gcol] = f2bf(rn);
            }
}

// out = [h|read_new] @ W_out^T + b_out (fp32 to d_out)
__global__ __launch_bounds__(256) void k_out(const u16* __restrict__ hrn, const u16* __restrict__ Wo,
                                             const float* __restrict__ b_out, float* __restrict__ out)
{
    gemm_nt_core<9>(hrn, 576, Wo, 576, blockIdx.x * 128, 0,
        [&](int r, int c, float v) { out[r * 64 + c] = v + b_out[c]; });
}

extern "C" void kernel_launch(void* const* d_in, const int* in_sizes, int n_in,
                              void* d_out, int out_size, void* d_ws, size_t ws_size,
                              hipStream_t stream)
{
    const float* x        = (const float*)d_in[0];
    const float* h_prev   = (const float*)d_in[1];
    const float* c_prev   = (const float*)d_in[2];
    const float* rwp      = (const float*)d_in[3];
    const float* memory   = (const float*)d_in[4];
    const float* W_ih     = (const float*)d_in[5];
    const float* b_ih     = (const float*)d_in[6];
    const float* W_hh     = (const float*)d_in[7];
    const float* b_hh     = (const float*)d_in[8];
    const float* W_read   = (const float*)d_in[9];
    const float* b_read   = (const float*)d_in[10];
    const float* W_write  = (const float*)d_in[11];
    const float* b_write  = (const float*)d_in[12];
    const float* W_erase  = (const float*)d_in[13];
    const float* b_erase  = (const float*)d_in[14];
    const float* W_add    = (const float*)d_in[15];
    const float* b_add    = (const float*)d_in[16];
    const float* W_out    = (const float*)d_in[17];
    const float* b_out    = (const float*)d_in[18];
    float* out = (float*)d_out;

    char* w = (char*)d_ws;
    // workspace layout (bytes); rwp_bf aliases rw_bf (disjoint lifetimes),
    // gates aliases pre_read/pre_write (disjoint lifetimes).
    u16*   inp_h   = (u16*)(w + 0);            // 2048x640 bf16  (x | read_prev | h_prev)
    u16*   wcat    = (u16*)(w + 2621440);      // 2048x640 bf16  (W_ih | W_hh)
    u16*   rwp_bf  = (u16*)(w + 5242880);      // 2048x1024 bf16 (later: rw_bf)
    u16*   rw_bf   = rwp_bf;
    u16*   rw2_bf  = (u16*)(w + 9437184);      // 2048x1024 bf16
    u16*   memt    = (u16*)(w + 13631488);     // 64x1024 bf16 (memory^T)
    u16*   Wr      = (u16*)(w + 13762560);     // 1024x512 bf16
    u16*   Ww      = (u16*)(w + 14811136);     // 1024x512 bf16
    u16*   Wea     = (u16*)(w + 15859712);     // 128x512 bf16 (W_erase ; W_add)
    u16*   Wo      = (u16*)(w + 15990784);     // 64x576 bf16
    float* gates   = (float*)(w + 16064512);   // 2048x2048 fp32
    float* pre_r   = gates;                    // 2048x1024 fp32 (aliases gates)
    float* pre_w   = (float*)(w + 16064512 + 8388608);
    u16*   hrn     = (u16*)(w + 32841728);     // 2048x576 bf16 ([h | read_new])
    float* s_buf   = (float*)(w + 35201024);   // 2048 fp32
    float* erase_b = (float*)(w + 35209216);   // 2048x64 fp32
    float* add_b   = (float*)(w + 35733504);   // 2048x64 fp32

    k_convert<<<5668, 256, 0, stream>>>(x, h_prev, rwp, memory, W_ih, W_hh, W_read, W_write,
                                        W_erase, W_add, W_out,
                                        inp_h, wcat, rwp_bf, memt, Wr, Ww, Wea, Wo);
    k_gemm_readprev<<<dim3(16), 256, 0, stream>>>(rwp_bf, memt, inp_h);
    k_gates<<<dim3(16, 32), 256, 0, stream>>>(inp_h, wcat, b_ih, b_hh, gates);
    k_lstm<<<4096, 256, 0, stream>>>(gates, c_prev, hrn);
    k_rdwr<<<dim3(16, 16, 2), 256, 0, stream>>>(hrn, Wr, Ww, b_read, b_write, pre_r, pre_w);
    k_ea<<<dim3(16, 2), 256, 0, stream>>>(hrn, Wea, b_erase, b_add, erase_b, add_b);
    k_softmax<<<2048, 256, 0, stream>>>(pre_r, pre_w, rw_bf, rw2_bf, s_buf);
    k_readnew<<<16, 256, 0, stream>>>(rw_bf, rw2_bf, memt, erase_b, add_b, s_buf, hrn);
    k_out<<<16, 256, 0, stream>>>(hrn, Wo, b_out, out);
}

// Round 2
// 190.683 us; speedup vs baseline: 1.3314x; 1.3314x over previous
//
#include <hip/hip_runtime.h>
#include <hip/hip_bf16.h>

// NTM cell on MI355X. B=2048, IN=64, CTRL=512, M=1024, V=64, OUT=64.
// All GEMMs NT via bf16 MFMA 16x16x32, BK=128, LDS row stride 136 (+8 pad).
// gates GEMM has LSTM fused in epilogue (wcat rows reordered: block col = gate*16 + j%16).
// read_prev / read_new are split-K GEMMs accumulating fp32 via atomicAdd (linear, exact).

typedef unsigned short u16;
typedef __attribute__((ext_vector_type(8))) short bf16x8;
typedef __attribute__((ext_vector_type(4))) float f32x4;

#define MFMA_BF16(a, b, c) __builtin_amdgcn_mfma_f32_16x16x32_bf16((a), (b), (c), 0, 0, 0)
#define LDW 136

__device__ __forceinline__ u16 f2bf(float f) {
    union { float f; unsigned int u; } a; a.f = f;
    return (u16)((a.u + 0x7FFFu + ((a.u >> 16) & 1u)) >> 16);
}

__device__ __forceinline__ void pack_store4(float a0, float a1, float a2, float a3, u16* d) {
    union { __hip_bfloat162 h[2]; uint2 u; } cv;
    cv.h[0] = __float22bfloat162_rn(make_float2(a0, a1));
    cv.h[1] = __float22bfloat162_rn(make_float2(a2, a3));
    *(uint2*)d = cv.u;
}

__device__ __forceinline__ void cvt4(const float* __restrict__ s, u16* __restrict__ d) {
    float4 v = *(const float4*)s;
    pack_store4(v.x, v.y, v.z, v.w, d);
}

__device__ __forceinline__ uint4 cvt8u(const float* __restrict__ s) {
    float4 v0 = *(const float4*)(s);
    float4 v1 = *(const float4*)(s + 4);
    union { __hip_bfloat162 h[4]; uint4 u; } r;
    r.h[0] = __float22bfloat162_rn(make_float2(v0.x, v0.y));
    r.h[1] = __float22bfloat162_rn(make_float2(v0.z, v0.w));
    r.h[2] = __float22bfloat162_rn(make_float2(v1.x, v1.y));
    r.h[3] = __float22bfloat162_rn(make_float2(v1.z, v1.w));
    return r.u;
}

__device__ __forceinline__ float sigf(float x) { return 1.f / (1.f + __expf(-x)); }
__device__ __forceinline__ float fast_tanh(float x) { return 1.f - 2.f / (__expf(2.f * x) + 1.f); }

// ---------------------------------------------------------------------------
// Convert fp32 -> bf16 staging buffers, reorder weights, transpose memory,
// zero the two fp32 atomic-accumulator buffers. Jobs in float4 units.
// ---------------------------------------------------------------------------
__global__ __launch_bounds__(256) void k_convert(
    const float* __restrict__ x, const float* __restrict__ h_prev, const float* __restrict__ rwp,
    const float* __restrict__ memory, const float* __restrict__ W_ih, const float* __restrict__ W_hh,
    const float* __restrict__ W_read, const float* __restrict__ W_write, const float* __restrict__ W_erase,
    const float* __restrict__ W_add, const float* __restrict__ W_out,
    u16* inp_h, u16* wcat, u16* rwp_bf, u16* Wcat2, u16* Wo_r, u16* memt,
    float* rp_f32, float* rn_f32)
{
    int t = blockIdx.x * 256 + threadIdx.x;
    if (t < 32768) { int r = t >> 4, c = (t & 15) * 4; cvt4(x + r * 64 + c, inp_h + r * 576 + c); return; }
    t -= 32768;
    if (t < 262144) { int r = t >> 7, c = (t & 127) * 4; cvt4(h_prev + r * 512 + c, inp_h + r * 576 + 64 + c); return; }
    t -= 262144;
    if (t < 65536) {  // W_ih: row reorder (gate interleave) + col swap (rp|x)
        int r = t >> 5, c = (t & 31) * 4;
        int g = r >> 9, j = r & 511;
        int rn = (j >> 4) * 64 + (g << 4) + (j & 15);
        int cd = (c < 64) ? c + 64 : c - 64;
        cvt4(W_ih + r * 128 + c, wcat + rn * 640 + cd); return;
    }
    t -= 65536;
    if (t < 262144) {  // W_hh: row reorder
        int r = t >> 7, c = (t & 127) * 4;
        int g = r >> 9, j = r & 511;
        int rn = (j >> 4) * 64 + (g << 4) + (j & 15);
        cvt4(W_hh + r * 512 + c, wcat + rn * 640 + 128 + c); return;
    }
    t -= 262144;
    if (t < 524288) { cvt4(rwp + t * 4, rwp_bf + t * 4); return; }
    t -= 524288;
    if (t < 131072) { cvt4(W_read + t * 4, Wcat2 + t * 4); return; }
    t -= 131072;
    if (t < 131072) { cvt4(W_write + t * 4, Wcat2 + 524288 + t * 4); return; }
    t -= 131072;
    if (t < 8192) { cvt4(W_erase + t * 4, Wcat2 + 1048576 + t * 4); return; }
    t -= 8192;
    if (t < 8192) { cvt4(W_add + t * 4, Wcat2 + 1081344 + t * 4); return; }
    t -= 8192;
    if (t < 9216) {  // W_out: K reorder to [rn(64) | h(512)]
        int r = t / 144, c = (t % 144) * 4;
        int cd = (c < 512) ? c + 64 : c - 512;
        cvt4(W_out + r * 576 + c, Wo_r + r * 576 + cd); return;
    }
    t -= 9216;
    if (t < 16384) {  // memory^T -> memt (64 x 1024)
        int v = t >> 8, m = (t & 255) * 4;
        pack_store4(memory[m * 64 + v], memory[(m + 1) * 64 + v],
                    memory[(m + 2) * 64 + v], memory[(m + 3) * 64 + v], memt + v * 1024 + m);
        return;
    }
    t -= 16384;
    if (t < 32768) { *(float4*)(rp_f32 + t * 4) = float4{0.f, 0.f, 0.f, 0.f}; return; }
    t -= 32768;
    if (t < 32768) { *(float4*)(rn_f32 + t * 4) = float4{0.f, 0.f, 0.f, 0.f}; return; }
}

// ---------------------------------------------------------------------------
// read_prev partial: rp_f32 += rwp_bf[:, k0:k0+512] @ memt[:, k0:k0+512]^T
// BM=64, BK=128, grid (32 m-blocks, 2 k-halves). atomicAdd fp32.
// ---------------------------------------------------------------------------
__global__ __launch_bounds__(256) void k_readprev(const u16* __restrict__ rwp_bf,
                                                  const u16* __restrict__ memt,
                                                  float* __restrict__ rp)
{
    __shared__ u16 As[64 * LDW];
    __shared__ u16 Bs[64 * LDW];
    const int tid = threadIdx.x, w = tid >> 6, lane = tid & 63;
    const int lrow = lane & 15, lq = lane >> 4;
    const int m0 = blockIdx.x * 64, k0 = blockIdx.y * 512;
    f32x4 acc[4] = {};
    for (int kt = 0; kt < 4; ++kt) {
#pragma unroll
        for (int i = 0; i < 4; ++i) {
            int idx = i * 256 + tid, r = idx >> 4, c = (idx & 15) * 8;
            *(uint4*)(&As[r * LDW + c]) = *(const uint4*)(rwp_bf + (m0 + r) * 1024 + k0 + kt * 128 + c);
            *(uint4*)(&Bs[r * LDW + c]) = *(const uint4*)(memt + r * 1024 + k0 + kt * 128 + c);
        }
        __syncthreads();
#pragma unroll
        for (int kk = 0; kk < 128; kk += 32) {
            bf16x8 a  = *(const bf16x8*)(&As[(16 * w + lrow) * LDW + kk + 8 * lq]);
            bf16x8 b0 = *(const bf16x8*)(&Bs[(lrow) * LDW + kk + 8 * lq]);
            bf16x8 b1 = *(const bf16x8*)(&Bs[(16 + lrow) * LDW + kk + 8 * lq]);
            bf16x8 b2 = *(const bf16x8*)(&Bs[(32 + lrow) * LDW + kk + 8 * lq]);
            bf16x8 b3 = *(const bf16x8*)(&Bs[(48 + lrow) * LDW + kk + 8 * lq]);
            acc[0] = MFMA_BF16(a, b0, acc[0]);
            acc[1] = MFMA_BF16(a, b1, acc[1]);
            acc[2] = MFMA_BF16(a, b2, acc[2]);
            acc[3] = MFMA_BF16(a, b3, acc[3]);
        }
        __syncthreads();
    }
#pragma unroll
    for (int nj = 0; nj < 4; ++nj)
#pragma unroll
        for (int r = 0; r < 4; ++r) {
            int row = m0 + 16 * w + 4 * lq + r, col = 16 * nj + lrow;
            atomicAdd(&rp[row * 64 + col], acc[nj][r]);
        }
}

// ---------------------------------------------------------------------------
// gates GEMM + fused LSTM. A-K layout: [read_prev(64, fp32 cvt) | x(64) | h_prev(512)].
// wcat rows pre-reordered so block col = gate*16 + (j & 15), j = bn*16 + lrow.
// Epilogue computes c, h directly; writes h (bf16) to hrn.
// ---------------------------------------------------------------------------
__global__ __launch_bounds__(256) void k_gates(const u16* __restrict__ inp_h, const float* __restrict__ rp,
                                               const u16* __restrict__ wcat,
                                               const float* __restrict__ b_ih, const float* __restrict__ b_hh,
                                               const float* __restrict__ c_prev, u16* __restrict__ hrn)
{
    __shared__ u16 As[128 * LDW];
    __shared__ u16 Bs[64 * LDW];
    const int tid = threadIdx.x, w = tid >> 6, lane = tid & 63;
    const int lrow = lane & 15, lq = lane >> 4;
    const int m0 = blockIdx.x * 128, bn = blockIdx.y;
    const u16* Bbase = wcat + bn * 64 * 640;
    f32x4 acc[2][4] = {};
    for (int kt = 0; kt < 5; ++kt) {
#pragma unroll
        for (int i = 0; i < 8; ++i) {
            int idx = i * 256 + tid, r = idx >> 4, c = (idx & 15) * 8;
            int ak = kt * 128 + c;
            uint4 v;
            if (ak < 64) v = cvt8u(rp + (m0 + r) * 64 + ak);
            else         v = *(const uint4*)(inp_h + (m0 + r) * 576 + (ak - 64));
            *(uint4*)(&As[r * LDW + c]) = v;
        }
#pragma unroll
        for (int i = 0; i < 4; ++i) {
            int idx = i * 256 + tid, r = idx >> 4, c = (idx & 15) * 8;
            *(uint4*)(&Bs[r * LDW + c]) = *(const uint4*)(Bbase + r * 640 + kt * 128 + c);
        }
        __syncthreads();
#pragma unroll
        for (int kk = 0; kk < 128; kk += 32) {
            bf16x8 a0 = *(const bf16x8*)(&As[(32 * w + lrow) * LDW + kk + 8 * lq]);
            bf16x8 a1 = *(const bf16x8*)(&As[(32 * w + 16 + lrow) * LDW + kk + 8 * lq]);
            bf16x8 b0 = *(const bf16x8*)(&Bs[(lrow) * LDW + kk + 8 * lq]);
            bf16x8 b1 = *(const bf16x8*)(&Bs[(16 + lrow) * LDW + kk + 8 * lq]);
            bf16x8 b2 = *(const bf16x8*)(&Bs[(32 + lrow) * LDW + kk + 8 * lq]);
            bf16x8 b3 = *(const bf16x8*)(&Bs[(48 + lrow) * LDW + kk + 8 * lq]);
            acc[0][0] = MFMA_BF16(a0, b0, acc[0][0]);
            acc[0][1] = MFMA_BF16(a0, b1, acc[0][1]);
            acc[0][2] = MFMA_BF16(a0, b2, acc[0][2]);
            acc[0][3] = MFMA_BF16(a0, b3, acc[0][3]);
            acc[1][0] = MFMA_BF16(a1, b0, acc[1][0]);
            acc[1][1] = MFMA_BF16(a1, b1, acc[1][1]);
            acc[1][2] = MFMA_BF16(a1, b2, acc[1][2]);
            acc[1][3] = MFMA_BF16(a1, b3, acc[1][3]);
        }
        __syncthreads();
    }
    const int j = bn * 16 + lrow;
    const float bI = b_ih[j] + b_hh[j];
    const float bF = b_ih[512 + j] + b_hh[512 + j];
    const float bG = b_ih[1024 + j] + b_hh[1024 + j];
    const float bO = b_ih[1536 + j] + b_hh[1536 + j];
#pragma unroll
    for (int mi = 0; mi < 2; ++mi)
#pragma unroll
        for (int r = 0; r < 4; ++r) {
            int row = m0 + 32 * w + 16 * mi + 4 * lq + r;
            float ig = sigf(acc[mi][0][r] + bI);
            float fg = sigf(acc[mi][1][r] + bF);
            float gg = fast_tanh(acc[mi][2][r] + bG);
            float og = sigf(acc[mi][3][r] + bO);
            float c = fg * c_prev[row * 512 + j] + ig * gg;
            hrn[row * 512 + j] = f2bf(og * fast_tanh(c));
        }
}

// ---------------------------------------------------------------------------
// heads: [pre_read | pre_write | erase | add] = h @ [Wr;Ww;We;Wa]^T + biases.
// grid (16, 34): bn<16 pre_r, <32 pre_w, ==32 erase(sig), ==33 add(tanh).
// ---------------------------------------------------------------------------
__global__ __launch_bounds__(256) void k_heads(const u16* __restrict__ hrn, const u16* __restrict__ Wcat2,
                                               const float* __restrict__ b_read, const float* __restrict__ b_write,
                                               const float* __restrict__ b_erase, const float* __restrict__ b_add,
                                               float* __restrict__ pre_r, float* __restrict__ pre_w,
                                               float* __restrict__ erase, float* __restrict__ add)
{
    __shared__ u16 As[128 * LDW];
    __shared__ u16 Bs[64 * LDW];
    const int tid = threadIdx.x, w = tid >> 6, lane = tid & 63;
    const int lrow = lane & 15, lq = lane >> 4;
    const int m0 = blockIdx.x * 128, bn = blockIdx.y;
    const u16* Bbase = Wcat2 + bn * 64 * 512;
    f32x4 acc[2][4] = {};
    for (int kt = 0; kt < 4; ++kt) {
#pragma unroll
        for (int i = 0; i < 8; ++i) {
            int idx = i * 256 + tid, r = idx >> 4, c = (idx & 15) * 8;
            *(uint4*)(&As[r * LDW + c]) = *(const uint4*)(hrn + (m0 + r) * 512 + kt * 128 + c);
        }
#pragma unroll
        for (int i = 0; i < 4; ++i) {
            int idx = i * 256 + tid, r = idx >> 4, c = (idx & 15) * 8;
            *(uint4*)(&Bs[r * LDW + c]) = *(const uint4*)(Bbase + r * 512 + kt * 128 + c);
        }
        __syncthreads();
#pragma unroll
        for (int kk = 0; kk < 128; kk += 32) {
            bf16x8 a0 = *(const bf16x8*)(&As[(32 * w + lrow) * LDW + kk + 8 * lq]);
            bf16x8 a1 = *(const bf16x8*)(&As[(32 * w + 16 + lrow) * LDW + kk + 8 * lq]);
            bf16x8 b0 = *(const bf16x8*)(&Bs[(lrow) * LDW + kk + 8 * lq]);
            bf16x8 b1 = *(const bf16x8*)(&Bs[(16 + lrow) * LDW + kk + 8 * lq]);
            bf16x8 b2 = *(const bf16x8*)(&Bs[(32 + lrow) * LDW + kk + 8 * lq]);
            bf16x8 b3 = *(const bf16x8*)(&Bs[(48 + lrow) * LDW + kk + 8 * lq]);
            acc[0][0] = MFMA_BF16(a0, b0, acc[0][0]);
            acc[0][1] = MFMA_BF16(a0, b1, acc[0][1]);
            acc[0][2] = MFMA_BF16(a0, b2, acc[0][2]);
            acc[0][3] = MFMA_BF16(a0, b3, acc[0][3]);
            acc[1][0] = MFMA_BF16(a1, b0, acc[1][0]);
            acc[1][1] = MFMA_BF16(a1, b1, acc[1][1]);
            acc[1][2] = MFMA_BF16(a1, b2, acc[1][2]);
            acc[1][3] = MFMA_BF16(a1, b3, acc[1][3]);
        }
        __syncthreads();
    }
#pragma unroll
    for (int mi = 0; mi < 2; ++mi)
#pragma unroll
        for (int nj = 0; nj < 4; ++nj)
#pragma unroll
            for (int r = 0; r < 4; ++r) {
                int row = m0 + 32 * w + 16 * mi + 4 * lq + r;
                int col = bn * 64 + 16 * nj + lrow;
                float v = acc[mi][nj][r];
                if (bn < 16)       pre_r[row * 1024 + col] = v + b_read[col];
                else if (bn < 32)  pre_w[row * 1024 + (col - 1024)] = v + b_write[col - 1024];
                else if (bn == 32) erase[row * 64 + (col - 2048)] = sigf(v + b_erase[col - 2048]);
                else               add[row * 64 + (col - 2112)] = fast_tanh(v + b_add[col - 2112]);
            }
}

__device__ __forceinline__ float wave_max(float v) {
#pragma unroll
    for (int o = 32; o > 0; o >>= 1) v = fmaxf(v, __shfl_xor(v, o, 64));
    return v;
}
__device__ __forceinline__ float wave_sum(float v) {
#pragma unroll
    for (int o = 32; o > 0; o >>= 1) v += __shfl_xor(v, o, 64);
    return v;
}

// dual softmax over M=1024; emits rw_bf, rw2_bf = rw*ww, s[b] = sum(rw*ww)
__global__ __launch_bounds__(256) void k_softmax(const float* __restrict__ pr, const float* __restrict__ pw,
                                                 u16* __restrict__ rw_bf, u16* __restrict__ rw2_bf,
                                                 float* __restrict__ s)
{
    int b = blockIdx.x, tid = threadIdx.x, w = tid >> 6, lane = tid & 63;
    const float* prb = pr + b * 1024;
    const float* pwb = pw + b * 1024;
    float vr[4], vw[4];
#pragma unroll
    for (int i = 0; i < 4; ++i) { vr[i] = prb[tid + 256 * i]; vw[i] = pwb[tid + 256 * i]; }
    float mr = fmaxf(fmaxf(vr[0], vr[1]), fmaxf(vr[2], vr[3]));
    float mw = fmaxf(fmaxf(vw[0], vw[1]), fmaxf(vw[2], vw[3]));
    mr = wave_max(mr); mw = wave_max(mw);
    __shared__ float red[4][4];
    if (lane == 0) { red[0][w] = mr; red[1][w] = mw; }
    __syncthreads();
    mr = fmaxf(fmaxf(red[0][0], red[0][1]), fmaxf(red[0][2], red[0][3]));
    mw = fmaxf(fmaxf(red[1][0], red[1][1]), fmaxf(red[1][2], red[1][3]));
    float er[4], ew[4], sr = 0.f, sw = 0.f;
#pragma unroll
    for (int i = 0; i < 4; ++i) {
        er[i] = __expf(vr[i] - mr); sr += er[i];
        ew[i] = __expf(vw[i] - mw); sw += ew[i];
    }
    sr = wave_sum(sr); sw = wave_sum(sw);
    __syncthreads();
    if (lane == 0) { red[2][w] = sr; red[3][w] = sw; }
    __syncthreads();
    sr = red[2][0] + red[2][1] + red[2][2] + red[2][3];
    sw = red[3][0] + red[3][1] + red[3][2] + red[3][3];
    float isr = 1.f / sr, isw = 1.f / sw, ss = 0.f;
#pragma unroll
    for (int i = 0; i < 4; ++i) {
        float a = er[i] * isr, cc = ew[i] * isw, r2 = a * cc;
        ss += r2;
        rw_bf[b * 1024 + tid + 256 * i] = f2bf(a);
        rw2_bf[b * 1024 + tid + 256 * i] = f2bf(r2);
    }
    ss = wave_sum(ss);
    __syncthreads();
    if (lane == 0) red[0][w] = ss;
    __syncthreads();
    if (tid == 0) s[b] = red[0][0] + red[0][1] + red[0][2] + red[0][3];
}

// ---------------------------------------------------------------------------
// read_new partial (split-K, linear in accs):
// rn_f32 += rw@memT_half - erase*(rw2@memT_half) + (kh==0)*add*s
// ---------------------------------------------------------------------------
__global__ __launch_bounds__(256) void k_readnew(const u16* __restrict__ rw, const u16* __restrict__ rw2,
                                                 const u16* __restrict__ memt,
                                                 const float* __restrict__ erase, const float* __restrict__ add,
                                                 const float* __restrict__ s, float* __restrict__ rn)
{
    __shared__ u16 As1[64 * LDW];
    __shared__ u16 As2[64 * LDW];
    __shared__ u16 Bs[64 * LDW];
    const int tid = threadIdx.x, w = tid >> 6, lane = tid & 63;
    const int lrow = lane & 15, lq = lane >> 4;
    const int m0 = blockIdx.x * 64, k0 = blockIdx.y * 512;
    f32x4 acc1[4] = {}, acc2[4] = {};
    for (int kt = 0; kt < 4; ++kt) {
#pragma unroll
        for (int i = 0; i < 4; ++i) {
            int idx = i * 256 + tid, r = idx >> 4, c = (idx & 15) * 8;
            *(uint4*)(&As1[r * LDW + c]) = *(const uint4*)(rw + (m0 + r) * 1024 + k0 + kt * 128 + c);
            *(uint4*)(&As2[r * LDW + c]) = *(const uint4*)(rw2 + (m0 + r) * 1024 + k0 + kt * 128 + c);
            *(uint4*)(&Bs[r * LDW + c])  = *(const uint4*)(memt + r * 1024 + k0 + kt * 128 + c);
        }
        __syncthreads();
#pragma unroll
        for (int kk = 0; kk < 128; kk += 32) {
            bf16x8 a  = *(const bf16x8*)(&As1[(16 * w + lrow) * LDW + kk + 8 * lq]);
            bf16x8 a2 = *(const bf16x8*)(&As2[(16 * w + lrow) * LDW + kk + 8 * lq]);
            bf16x8 b0 = *(const bf16x8*)(&Bs[(lrow) * LDW + kk + 8 * lq]);
            bf16x8 b1 = *(const bf16x8*)(&Bs[(16 + lrow) * LDW + kk + 8 * lq]);
            bf16x8 b2 = *(const bf16x8*)(&Bs[(32 + lrow) * LDW + kk + 8 * lq]);
            bf16x8 b3 = *(const bf16x8*)(&Bs[(48 + lrow) * LDW + kk + 8 * lq]);
            acc1[0] = MFMA_BF16(a, b0, acc1[0]);
            acc1[1] = MFMA_BF16(a, b1, acc1[1]);
            acc1[2] = MFMA_BF16(a, b2, acc1[2]);
            acc1[3] = MFMA_BF16(a, b3, acc1[3]);
            acc2[0] = MFMA_BF16(a2, b0, acc2[0]);
            acc2[1] = MFMA_BF16(a2, b1, acc2[1]);
            acc2[2] = MFMA_BF16(a2, b2, acc2[2]);
            acc2[3] = MFMA_BF16(a2, b3, acc2[3]);
        }
        __syncthreads();
    }
    const int kh = blockIdx.y;
#pragma unroll
    for (int nj = 0; nj < 4; ++nj)
#pragma unroll
        for (int r = 0; r < 4; ++r) {
            int row = m0 + 16 * w + 4 * lq + r, col = 16 * nj + lrow;
            float contrib = acc1[nj][r] - erase[row * 64 + col] * acc2[nj][r];
            if (kh == 0) contrib += add[row * 64 + col] * s[row];
            atomicAdd(&rn[row * 64 + col], contrib);
        }
}

// ---------------------------------------------------------------------------
// out = [read_new | h] @ Wo_r^T + b_out.  A-K: [rn(64, fp32 cvt) | h(512)].
// BM=64, kt 0..3 full 128-wide, kt4 = 64-wide tail.
// ---------------------------------------------------------------------------
__global__ __launch_bounds__(256) void k_out(const u16* __restrict__ hrn, const float* __restrict__ rn,
                                             const u16* __restrict__ Wo_r, const float* __restrict__ b_out,
                                             float* __restrict__ out)
{
    __shared__ u16 As[64 * LDW];
    __shared__ u16 Bs[64 * LDW];
    const int tid = threadIdx.x, w = tid >> 6, lane = tid & 63;
    const int lrow = lane & 15, lq = lane >> 4;
    const int m0 = blockIdx.x * 64;
    f32x4 acc[4] = {};
    for (int kt = 0; kt < 4; ++kt) {
#pragma unroll
        for (int i = 0; i < 4; ++i) {
            int idx = i * 256 + tid, r = idx >> 4, c = (idx & 15) * 8;
            int ak = kt * 128 + c;
            uint4 v;
            if (ak < 64) v = cvt8u(rn + (m0 + r) * 64 + ak);
            else         v = *(const uint4*)(hrn + (m0 + r) * 512 + (ak - 64));
            *(uint4*)(&As[r * LDW + c]) = v;
            *(uint4*)(&Bs[r * LDW + c]) = *(const uint4*)(Wo_r + r * 576 + kt * 128 + c);
        }
        __syncthreads();
#pragma unroll
        for (int kk = 0; kk < 128; kk += 32) {
            bf16x8 a  = *(const bf16x8*)(&As[(16 * w + lrow) * LDW + kk + 8 * lq]);
            bf16x8 b0 = *(const bf16x8*)(&Bs[(lrow) * LDW + kk + 8 * lq]);
            bf16x8 b1 = *(const bf16x8*)(&Bs[(16 + lrow) * LDW + kk + 8 * lq]);
            bf16x8 b2 = *(const bf16x8*)(&Bs[(32 + lrow) * LDW + kk + 8 * lq]);
            bf16x8 b3 = *(const bf16x8*)(&Bs[(48 + lrow) * LDW + kk + 8 * lq]);
            acc[0] = MFMA_BF16(a, b0, acc[0]);
            acc[1] = MFMA_BF16(a, b1, acc[1]);
            acc[2] = MFMA_BF16(a, b2, acc[2]);
            acc[3] = MFMA_BF16(a, b3, acc[3]);
        }
        __syncthreads();
    }
    // tail: ak 512..575 -> hrn cols 448..511, Wo_r cols 512..575
#pragma unroll
    for (int i = 0; i < 2; ++i) {
        int idx = i * 256 + tid, r = idx >> 3, c = (idx & 7) * 8;
        *(uint4*)(&As[r * LDW + c]) = *(const uint4*)(hrn + (m0 + r) * 512 + 448 + c);
        *(uint4*)(&Bs[r * LDW + c]) = *(const uint4*)(Wo_r + r * 576 + 512 + c);
    }
    __syncthreads();
#pragma unroll
    for (int kk = 0; kk < 64; kk += 32) {
        bf16x8 a  = *(const bf16x8*)(&As[(16 * w + lrow) * LDW + kk + 8 * lq]);
        bf16x8 b0 = *(const bf16x8*)(&Bs[(lrow) * LDW + kk + 8 * lq]);
        bf16x8 b1 = *(const bf16x8*)(&Bs[(16 + lrow) * LDW + kk + 8 * lq]);
        bf16x8 b2 = *(const bf16x8*)(&Bs[(32 + lrow) * LDW + kk + 8 * lq]);
        bf16x8 b3 = *(const bf16x8*)(&Bs[(48 + lrow) * LDW + kk + 8 * lq]);
        acc[0] = MFMA_BF16(a, b0, acc[0]);
        acc[1] = MFMA_BF16(a, b1, acc[1]);
        acc[2] = MFMA_BF16(a, b2, acc[2]);
        acc[3] = MFMA_BF16(a, b3, acc[3]);
    }
#pragma unroll
    for (int nj = 0; nj < 4; ++nj)
#pragma unroll
        for (int r = 0; r < 4; ++r) {
            int row = m0 + 16 * w + 4 * lq + r, col = 16 * nj + lrow;
            out[row * 64 + col] = acc[nj][r] + b_out[col];
        }
}

extern "C" void kernel_launch(void* const* d_in, const int* in_sizes, int n_in,
                              void* d_out, int out_size, void* d_ws, size_t ws_size,
                              hipStream_t stream)
{
    const float* x        = (const float*)d_in[0];
    const float* h_prev   = (const float*)d_in[1];
    const float* c_prev   = (const float*)d_in[2];
    const float* rwp      = (const float*)d_in[3];
    const float* memory   = (const float*)d_in[4];
    const float* W_ih     = (const float*)d_in[5];
    const float* b_ih     = (const float*)d_in[6];
    const float* W_hh     = (const float*)d_in[7];
    const float* b_hh     = (const float*)d_in[8];
    const float* W_read   = (const float*)d_in[9];
    const float* b_read   = (const float*)d_in[10];
    const float* W_write  = (const float*)d_in[11];
    const float* b_write  = (const float*)d_in[12];
    const float* W_erase  = (const float*)d_in[13];
    const float* b_erase  = (const float*)d_in[14];
    const float* W_add    = (const float*)d_in[15];
    const float* b_add    = (const float*)d_in[16];
    const float* W_out    = (const float*)d_in[17];
    const float* b_out    = (const float*)d_in[18];
    float* out = (float*)d_out;

    char* wsp = (char*)d_ws;
    u16*   inp_h  = (u16*)(wsp + 0);           // 2048x576 bf16 [x | h_prev]
    u16*   wcat   = (u16*)(wsp + 2359296);     // 2048x640 bf16 (reordered [rp|x|h] x gate-interleaved rows)
    u16*   memt   = (u16*)(wsp + 4980736);     // 64x1024 bf16 memory^T
    u16*   rwp_bf = (u16*)(wsp + 5111808);     // 2048x1024 bf16
    u16*   Wcat2  = (u16*)(wsp + 9306112);     // 2176x512 bf16 [Wr;Ww;We;Wa]
    u16*   Wo_r   = (u16*)(wsp + 11534336);    // 64x576 bf16 (K reordered [rn|h])
    float* rp_f32 = (float*)(wsp + 11608064);  // 2048x64 fp32 (atomic acc)
    u16*   hrn    = (u16*)(wsp + 12132352);    // 2048x512 bf16 (h)
    float* pre_r  = (float*)(wsp + 14229504);  // 2048x1024 fp32
    float* pre_w  = (float*)(wsp + 22618112);  // 2048x1024 fp32
    u16*   rw_bf  = (u16*)(wsp + 31006720);    // 2048x1024 bf16
    u16*   rw2_bf = (u16*)(wsp + 35201024);    // 2048x1024 bf16
    float* rn_f32 = (float*)(wsp + 39395328);  // 2048x64 fp32 (atomic acc)
    float* erase  = (float*)(wsp + 39919616);  // 2048x64 fp32
    float* add    = (float*)(wsp + 40443904);  // 2048x64 fp32
    float* s_buf  = (float*)(wsp + 40968192);  // 2048 fp32

    k_convert<<<5924, 256, 0, stream>>>(x, h_prev, rwp, memory, W_ih, W_hh, W_read, W_write,
                                        W_erase, W_add, W_out,
                                        inp_h, wcat, rwp_bf, Wcat2, Wo_r, memt, rp_f32, rn_f32);
    k_readprev<<<dim3(32, 2), 256, 0, stream>>>(rwp_bf, memt, rp_f32);
    k_gates<<<dim3(16, 32), 256, 0, stream>>>(inp_h, rp_f32, wcat, b_ih, b_hh, c_prev, hrn);
    k_heads<<<dim3(16, 34), 256, 0, stream>>>(hrn, Wcat2, b_read, b_write, b_erase, b_add,
                                              pre_r, pre_w, erase, add);
    k_softmax<<<2048, 256, 0, stream>>>(pre_r, pre_w, rw_bf, rw2_bf, s_buf);
    k_readnew<<<dim3(32, 2), 256, 0, stream>>>(rw_bf, rw2_bf, memt, erase, add, s_buf, rn_f32);
    k_out<<<32, 256, 0, stream>>>(hrn, rn_f32, Wo_r, b_out, out);
}